// Round 14
// baseline (283.553 us; speedup 1.0000x reference)
//
#include <hip/hip_runtime.h>
#include <math.h>

#define DEVI static __device__ __forceinline__

constexpr int Bn = 4, Cn = 4, Pn = 16384, Sn = 8192, Kn = 16;
constexpr float GN_N = 131072.0f;   // S*K per (b,channel)
constexpr int PART_STRIDE = 96;     // 79 used
constexpr int ST_CHUNKS = 256;      // k_stats grid.x
constexpr int GD = 16;              // grid cells per dim
constexpr int NCELL = GD * GD * GD; // 4096
constexpr float BND = 5.5f;         // fixed bounds (edge cells extend to inf)
constexpr float CH = 0.6875f;       // 11/16, exact in f32
constexpr float INVH = 1.4545455f;  // 16/11 (binning only; consistent everywhere)
constexpr float SLACK = 1e-3f;      // >> pd-vs-exact-dist rounding gap (~2e-5)

// non-contracted f32 ops (exact pd must match np's mul/add order)
DEVI float mulrn(float a, float b){ return __fmul_rn(a, b); }
DEVI float addrn(float a, float b){ return __fadd_rn(a, b); }
DEVI float subrn(float a, float b){ return __fsub_rn(a, b); }
DEVI float leaky(float v, float s){ return v >= 0.0f ? v : s * v; }

DEVI int clampi(int v, int lo, int hi){ return v < lo ? lo : (v > hi ? hi : v); }

// DPP row_shr:1 == shfl_up(x,1,16) within each 16-lane row (group == row).
DEVI float dpp_up1f(float x){
  int xi = __builtin_bit_cast(int, x);
  int r = __builtin_amdgcn_update_dpp(xi, xi, 0x111, 0xF, 0xF, false);
  return __builtin_bit_cast(float, r);
}
DEVI int dpp_up1i(int x){
  return __builtin_amdgcn_update_dpp(x, x, 0x111, 0xF, 0xF, false);
}
// lane (i|15) broadcast within each 16-lane group
DEVI float swz15(float x){
  int xi = __builtin_bit_cast(int, x);
  int r = __builtin_amdgcn_ds_swizzle(xi, 0x1FF);
  return __builtin_bit_cast(float, r);
}
DEVI int swz15i(int x){ return __builtin_amdgcn_ds_swizzle(x, 0x1FF); }

// cell binning — identical function used by hist/scatter/query
DEVI int cellof(float4 v, int &cx, int &cy, int &cz){
  cx = clampi((int)((v.x + BND) * INVH), 0, GD - 1);
  cy = clampi((int)((v.y + BND) * INVH), 0, GD - 1);
  cz = clampi((int)((v.z + BND) * INVH), 0, GD - 1);
  return (cx * GD + cy) * GD + cz;
}

// min dist^2 contribution of one dim; edge cells extend outward to infinity
DEVI float cm1(float q, int c){
  float lo = -BND + c * CH, hi = lo + CH;
  float d = 0.f;
  if (c > 0      && q < lo) d = lo - q;
  if (c < GD - 1 && q > hi) d = q - hi;
  return d * d;
}

// ---------------- K1: pack coords + norm; point + query histograms ---------
// hist zeroed by hipMemsetAsync before this kernel. Query cells recomputed
// directly from x (no pk dependency), so hist fuses into the pack pass.
__global__ void k_pack(const float* __restrict__ x, const int* __restrict__ perm,
                       float4* __restrict__ pk, int* __restrict__ hist){
  int i = blockIdx.x * 256 + threadIdx.x;       // 0 .. B*P-1
  int b = i >> 14, p = i & (Pn - 1);
  const float* xb = x + (size_t)b * Cn * Pn;
  float x0 = xb[p], x1 = xb[Pn + p], x2 = xb[2 * Pn + p];
  float n = addrn(addrn(mulrn(x0, x0), mulrn(x1, x1)), mulrn(x2, x2));
  pk[i] = make_float4(x0, x1, x2, n);
  int cx, cy, cz;
  int c = cellof(make_float4(x0, x1, x2, n), cx, cy, cz);
  atomicAdd(&hist[b * NCELL + c], 1);
  if (i < Bn * Sn){
    int b2 = i >> 13;
    int q = perm[i];
    const float* xb2 = x + (size_t)b2 * Cn * Pn;
    float4 qv = make_float4(xb2[q], xb2[Pn + q], xb2[2 * Pn + q], 0.f);
    int c2 = cellof(qv, cx, cy, cz);
    atomicAdd(&hist[(4 + b2) * NCELL + c2], 1);
  }
}

// ---------------- K1c: exclusive scan per unit (8 units x 4096 cells) ------
__launch_bounds__(1024)
__global__ void k_scan(const int* __restrict__ hist, int* __restrict__ cellstart,
                       int* __restrict__ cursor){
  __shared__ int sh[1024];
  const int u = blockIdx.x, t = threadIdx.x;
  const int base = u * NCELL + t * 4;
  int sum = 0;
#pragma unroll
  for (int i = 0; i < 4; ++i) sum += hist[base + i];
  sh[t] = sum;
  __syncthreads();
  for (int off = 1; off < 1024; off <<= 1){
    int v = (t >= off) ? sh[t - off] : 0;
    __syncthreads();
    sh[t] += v;
    __syncthreads();
  }
  int run = sh[t] - sum;                        // exclusive
  const int cbase = u * (NCELL + 1) + t * 4;
#pragma unroll
  for (int i = 0; i < 4; ++i){
    cellstart[cbase + i] = run;
    cursor[cbase + i] = run;
    run += hist[base + i];
  }
  if (t == 1023) cellstart[u * (NCELL + 1) + NCELL] = run;
}

// ---------------- K1d: scatter points into cell order; sort queries --------
__global__ void k_scatter(const float4* __restrict__ pk, const int* __restrict__ perm,
                          int* __restrict__ cursor, float4* __restrict__ spt,
                          int* __restrict__ sid, int* __restrict__ qord){
  int i = blockIdx.x * 256 + threadIdx.x;
  int b = i >> 14, p = i & (Pn - 1);
  float4 v = pk[i];
  int cx, cy, cz;
  int c = cellof(v, cx, cy, cz);
  int slot = atomicAdd(&cursor[b * (NCELL + 1) + c], 1);
  spt[b * Pn + slot] = v;
  sid[b * Pn + slot] = p;
  if (i < Bn * Sn){
    int b2 = i >> 13, s = i & (Sn - 1);
    int q = perm[i];
    int c2 = cellof(pk[b2 * Pn + q], cx, cy, cz);
    int slot2 = atomicAdd(&cursor[(4 + b2) * (NCELL + 1) + c2], 1);
    qord[b2 * Sn + slot2] = s;                  // queries sorted by cell
  }
}

// ---------------- K2: exact top-16 per (b,s): grid prune + 16-lane group ---
// 16 lanes per query; 16 cell-sorted queries per block; cellstart in LDS.
// RSCAN: software-pipelined strided point loop (prefetch next 16 while the
// current 16 are evaluated/inserted). On-shell z-columns are contiguous in
// spt: small columns (<=32 pts) scanned as ONE merged range (fewer per-cell
// overheads, longer pipelined runs); large columns keep per-cell z-pruning
// (dense regions, where the tight t15 prunes most z cells). Merged path only
// evaluates EXTRA points -> exact-compare gating keeps output identical.
// Insert machinery unchanged: sorted top-16, 1 rank/lane, key (pd desc,
// idx asc) == lax.top_k stable ties; arrival-order-independent.
#define RSCAN(J0, J1)                                                         \
  { int jb_ = (J0); const int je_ = (J1);                                     \
    float4 pv_; int pidx_;                                                    \
    bool pok_ = jb_ + lane16 < je_;                                           \
    if (pok_){ pv_ = spt[pb + jb_ + lane16]; pidx_ = sid[pb + jb_ + lane16]; }\
    for (; jb_ < je_; jb_ += 16){                                             \
      const float4 v = pv_; const int pi = pidx_; const bool ok = pok_;       \
      const int jn_ = jb_ + 16 + lane16;                                      \
      pok_ = jn_ < je_;                                                       \
      if (pok_){ pv_ = spt[pb + jn_]; pidx_ = sid[pb + jn_]; }                \
      float cpd = -INFINITY; int cpi = 0x7FFFFFFF;                            \
      if (ok){                                                                \
        const float dot = addrn(addrn(mulrn(v.x, qx), mulrn(v.y, qy)),        \
                                mulrn(v.z, qz));                              \
        cpd = subrn(subrn(mulrn(2.0f, dot), v.w), qw);                        \
        cpi = pi;                                                             \
      }                                                                       \
      const unsigned long long m0 =                                           \
        __ballot((cpd > t15) || (cpd == t15 && cpi < i15)) & gmask;           \
      unsigned long long mm = m0;                                             \
      while (mm){                                                             \
        const int src = __builtin_ctzll(mm);                                  \
        mm &= mm - 1;                                                         \
        const float cv = __shfl(cpd, src);                                    \
        const int   ci = __shfl(cpi, src);                                    \
        const float upv = dpp_up1f(lv);                                       \
        const int   upi = dpp_up1i(li);                                       \
        const bool keep = (lv > cv) || (lv == cv && li < ci);                 \
        const bool ins  = (!keep) &&                                          \
          (lane0 || (upv > cv) || (upv == cv && upi < ci));                   \
        lv = keep ? lv : (ins ? cv : upv);                                    \
        li = keep ? li : (ins ? ci : upi);                                    \
      }                                                                       \
      if (m0){ t15 = swz15(lv); i15 = swz15i(li); }                           \
    } }

__launch_bounds__(256)
__global__ void k_topk(const float4* __restrict__ pk, const float4* __restrict__ spt,
                       const int* __restrict__ sid, const int* __restrict__ cellstart,
                       const int* __restrict__ perm, const int* __restrict__ qord,
                       int* __restrict__ idx){
  __shared__ int lcs[NCELL + 1];                // 16388 B: whole batch table
  const int b = blockIdx.y;
  const int tid = threadIdx.x;
  const int lane = tid & 63;
  const int lane16 = lane & 15;
  const bool lane0 = (lane16 == 0);
  const int g = lane >> 4;
  const unsigned long long gmask = 0xFFFFull << (g * 16);
  const int s = qord[b * Sn + blockIdx.x * 16 + (tid >> 4)];  // sorted query

  const int cb = b * (NCELL + 1);
  for (int j = tid; j <= NCELL; j += 256) lcs[j] = cellstart[cb + j];

  const int q = perm[b * Sn + s];
  const float4 sv = pk[b * Pn + q];
  const float qx = sv.x, qy = sv.y, qz = sv.z, qw = sv.w;
  int qcx, qcy, qcz;
  cellof(sv, qcx, qcy, qcz);
  const int pb = b * Pn;
  __syncthreads();

  float lv = -INFINITY;  int li = 0x7FFFFFFF;   // my rank's (value, index)
  float t15 = -INFINITY; int i15 = 0x7FFFFFFF;  // rank-15 key (group-uniform)

  for (int r = 0; r < GD; ++r){
    if (r >= 1 && t15 > -1e37f){
      const float lb = (float)(r - 1) * CH;
      if (-(lb * lb) < t15 - SLACK) break;      // no farther shell can matter
    }
    const int x0 = clampi(qcx - r, 0, GD - 1), x1 = clampi(qcx + r, 0, GD - 1);
    const int y0 = clampi(qcy - r, 0, GD - 1), y1 = clampi(qcy + r, 0, GD - 1);
    for (int cx = x0; cx <= x1; ++cx){
      const int adx = cx > qcx ? cx - qcx : qcx - cx;
      const float bx = cm1(qx, cx);
      for (int cy = y0; cy <= y1; ++cy){
        const int ady = cy > qcy ? cy - qcy : qcy - cy;
        const float bxy = bx + cm1(qy, cy);
        // column prune: z-contribution >= 0, so bxy bounds the whole column
        if ((t15 > -1e37f) && -bxy < t15 - SLACK) continue;
        const int colb = (cx * GD + cy) * GD;
        if (adx == r || ady == r){              // full z-column is on the shell
          const int z0c = clampi(qcz - r, 0, GD - 1);
          const int z1c = clampi(qcz + r, 0, GD - 1);
          const int cj0 = lcs[colb + z0c], cj1 = lcs[colb + z1c + 1];
          if (cj0 == cj1) continue;             // column empty (monotone table)
          if (cj1 - cj0 <= 32){                 // sparse: one merged range
            RSCAN(cj0, cj1)
          } else {                              // dense: keep per-cell z-prune
            for (int cz = z0c; cz <= z1c; ++cz){
              const float m2_ = bxy + cm1(qz, cz);
              if ((t15 > -1e37f) && -m2_ < t15 - SLACK) continue;
              const int c_ = colb + cz;
              RSCAN(lcs[c_], lcs[c_ + 1])
            }
          }
        } else {                                // only |dz| == r on the shell
          int cz = qcz - r;
          if (cz >= 0){
            const float m2_ = bxy + cm1(qz, cz);
            if (!((t15 > -1e37f) && -m2_ < t15 - SLACK)){
              const int c_ = colb + cz;
              RSCAN(lcs[c_], lcs[c_ + 1])
            }
          }
          cz = qcz + r;
          if (cz <= GD - 1){
            const float m2_ = bxy + cm1(qz, cz);
            if (!((t15 > -1e37f) && -m2_ < t15 - SLACK)){
              const int c_ = colb + cz;
              RSCAN(lcs[c_], lcs[c_ + 1])
            }
          }
        }
      }
    }
  }

  idx[((size_t)(b * Sn + s)) * Kn + lane16] = li;
}
#undef RSCAN

// scramble: x1[b,c,s',k'] = x[b,c, idx[b, (16s'+k') & 8191, (16s'+k') >> 13]]
DEVI int idxq(const int* __restrict__ idxb, int f){
  return idxb[(f & (Sn - 1)) * Kn + (f >> 13)];
}

DEVI float wred(float v){
  v += __shfl_down(v, 32); v += __shfl_down(v, 16); v += __shfl_down(v, 8);
  v += __shfl_down(v, 4);  v += __shfl_down(v, 2);  v += __shfl_down(v, 1);
  return v;
}

// ---------------- K3: GN moment accumulation ----------------
// grid (256, B), block 256: thread -> (sp, kq); sp = chunk*32 + tid>>3, 2 k's.
__global__ void k_stats(const float4* __restrict__ pk, const float* __restrict__ x,
                        const int* __restrict__ idx, float* __restrict__ part){
  const int b = blockIdx.y, chunk = blockIdx.x, tid = threadIdx.x;
  const int sp = chunk * 32 + (tid >> 3);
  const int kq = tid & 7;
  const int* idxb = idx + b * Sn * Kn;
  const float* xw = x + ((size_t)b * Cn + 3) * Pn;

  float M10[55], mu10[10], M4[10], mu4[4];
#pragma unroll
  for (int i = 0; i < 55; ++i) M10[i] = 0.f;
#pragma unroll
  for (int i = 0; i < 10; ++i){ mu10[i] = 0.f; M4[i] = 0.f; }
#pragma unroll
  for (int i = 0; i < 4; ++i) mu4[i] = 0.f;

  const int qc = idxq(idxb, sp * 16);
  const float4 cv = pk[b * Pn + qc];

#pragma unroll
  for (int kk = 0; kk < 2; ++kk){
    const int k = kq * 2 + kk;
    const int qn = idxq(idxb, sp * 16 + k);
    const float4 pv = pk[b * Pn + qn];
    const float pw = xw[qn];
    const float dx = subrn(pv.x, cv.x), dy = subrn(pv.y, cv.y), dz = subrn(pv.z, cv.z);
    const float temp = sqrtf(addrn(addrn(mulrn(dx, dx), mulrn(dy, dy)), mulrn(dz, dz)));
    const float E[10] = {pv.x, pv.y, pv.z, cv.x, cv.y, cv.z, dx, dy, dz, temp};
    const float X[4]  = {pv.x, pv.y, pv.z, pw};
    int c = 0;
#pragma unroll
    for (int i = 0; i < 10; ++i){
      mu10[i] += E[i];
#pragma unroll
      for (int j = i; j < 10; ++j){ M10[c] += E[i] * E[j]; ++c; }
    }
    c = 0;
#pragma unroll
    for (int i = 0; i < 4; ++i){
      mu4[i] += X[i];
#pragma unroll
      for (int j = i; j < 4; ++j){ M4[c] += X[i] * X[j]; ++c; }
    }
  }

  __shared__ float red[4][80];
  const int wid = tid >> 6, ln = tid & 63;
#pragma unroll
  for (int i = 0; i < 55; ++i){ float v = wred(M10[i]); if (ln == 0) red[wid][i] = v; }
#pragma unroll
  for (int i = 0; i < 10; ++i){ float v = wred(mu10[i]); if (ln == 0) red[wid][55 + i] = v; }
#pragma unroll
  for (int i = 0; i < 10; ++i){ float v = wred(M4[i]); if (ln == 0) red[wid][65 + i] = v; }
#pragma unroll
  for (int i = 0; i < 4; ++i){ float v = wred(mu4[i]); if (ln == 0) red[wid][75 + i] = v; }
  __syncthreads();
  if (tid < 79){
    float sum = ((red[0][tid] + red[1][tid]) + red[2][tid]) + red[3][tid];
    part[(b * ST_CHUNKS + chunk) * PART_STRIDE + tid] = sum;
  }
}

// ---------------- K4: fold moments into per-(b,ch) scale/shift ----------------
__global__ void k_stats2(const float* __restrict__ part,
                         const float* __restrict__ pos_w, const float* __restrict__ conv_w,
                         const float* __restrict__ bn2_g, const float* __restrict__ bn2_b,
                         const float* __restrict__ bn_g,  const float* __restrict__ bn_b,
                         float2* __restrict__ stats){
  __shared__ float phalf[8][80];
  __shared__ float sacc[4][80];
  const int t = threadIdx.x;
  if (t < 640){
    const int pair = t / 80, i = t % 80;      // pair = b*2 + half
    if (i < 79){
      const int bb = pair >> 1, half = pair & 1;
      float a = 0.f;
      for (int c = half * 128; c < half * 128 + 128; ++c)
        a += part[(bb * ST_CHUNKS + c) * PART_STRIDE + i];
      phalf[pair][i] = a;
    }
  }
  __syncthreads();
  if (t < 320){
    const int bb = t / 80, i = t % 80;
    if (i < 79) sacc[bb][i] = phalf[bb * 2][i] + phalf[bb * 2 + 1][i];
  }
  __syncthreads();
  if (t >= 256) return;
  const int b = t >> 6, o = t & 63;
  const float* acc = sacc[b];
  float mean, ex2, gamma, beta;
  if (o < 32){                        // xc channels: conv path, bn_g/bn_b
    const float* w = conv_w + o * 4;
    float m = 0.f, e2 = 0.f; int id = 0;
#pragma unroll
    for (int i = 0; i < 4; ++i){
      m += w[i] * acc[75 + i];
#pragma unroll
      for (int j = i; j < 4; ++j){
        float t2 = w[i] * w[j] * acc[65 + id];
        e2 += (i == j) ? t2 : 2.0f * t2; ++id;
      }
    }
    mean = m / GN_N; ex2 = e2 / GN_N; gamma = bn_g[o]; beta = bn_b[o];
  } else {                            // pe channels: pos path, bn2_g/bn2_b
    const float* w = pos_w + (o - 32) * 10;
    float m = 0.f, e2 = 0.f; int id = 0;
#pragma unroll
    for (int i = 0; i < 10; ++i){
      m += w[i] * acc[55 + i];
#pragma unroll
      for (int j = i; j < 10; ++j){
        float t2 = w[i] * w[j] * acc[id];
        e2 += (i == j) ? t2 : 2.0f * t2; ++id;
      }
    }
    mean = m / GN_N; ex2 = e2 / GN_N; gamma = bn2_g[o - 32]; beta = bn2_b[o - 32];
  }
  const float var = fmaxf(ex2 - mean * mean, 0.f);
  const float rstd = 1.0f / sqrtf(var + 1e-5f);
  const float scale = rstd * gamma;
  stats[b * 64 + o] = make_float2(scale, beta - mean * scale);
}

// ---------------- K5: fused features + attention + output ----------------
// 16 lanes per s'; block = 16 s'. Output staged in padded LDS, then written
// as contiguous 64B row-segments.
__global__ void k_final(const float4* __restrict__ pk, const float* __restrict__ x,
                        const int* __restrict__ idx, const float2* __restrict__ stats,
                        const float* __restrict__ conv_w, const float* __restrict__ pos_w,
                        const float* __restrict__ att_w1, const float* __restrict__ att_w2,
                        const float* __restrict__ b1_w, const float* __restrict__ b2_w,
                        float* __restrict__ out){
  __shared__ float ob[68][17];                  // +1 pad: conflict-free stores
  const int b = blockIdx.y;
  const int tid = threadIdx.x;
  const int k = tid & 15;
  const int spl = tid >> 4;
  const int sp0 = blockIdx.x * 16;
  const int sp = sp0 + spl;
  const int* idxb = idx + b * Sn * Kn;
  const float* xw = x + ((size_t)b * Cn + 3) * Pn;

  const int qn = idxq(idxb, sp * 16 + k);
  const float4 pv = pk[b * Pn + qn];
  const float pw = xw[qn];
  const float cx = __shfl(pv.x, 0, 16), cy = __shfl(pv.y, 0, 16);
  const float cz = __shfl(pv.z, 0, 16), cw = __shfl(pw, 0, 16);
  const float dx = subrn(pv.x, cx), dy = subrn(pv.y, cy), dz = subrn(pv.z, cz);
  const float temp = sqrtf(addrn(addrn(mulrn(dx, dx), mulrn(dy, dy)), mulrn(dz, dz)));
  const float E[10]  = {pv.x, pv.y, pv.z, cx, cy, cz, dx, dy, dz, temp};
  const float X4[4]  = {pv.x, pv.y, pv.z, pw};
  const float2* stb = stats + b * 64;

  float feat[64];
  for (int o = 0; o < 32; ++o){       // xc
    float v = 0.f;
#pragma unroll
    for (int c = 0; c < 4; ++c) v = fmaf(conv_w[o * 4 + c], X4[c], v);
    const float2 sc = stb[o];
    feat[o] = leaky(fmaf(v, sc.x, sc.y), 0.2f);
  }
  for (int o = 0; o < 32; ++o){       // pe
    float v = 0.f;
#pragma unroll
    for (int c = 0; c < 10; ++c) v = fmaf(pos_w[o * 10 + c], E[c], v);
    const float2 sc = stb[32 + o];
    feat[32 + o] = leaky(fmaf(v, sc.x, sc.y), 0.2f);
  }

  float logit = 0.f;
  for (int h = 0; h < 32; ++h){
    float v = 0.f;
#pragma unroll
    for (int c = 0; c < 64; ++c) v = fmaf(att_w1[h * 64 + c], feat[c], v);
    logit = fmaf(att_w2[h], leaky(v, 0.2f), logit);
  }
  float mx = logit;
  mx = fmaxf(mx, __shfl_xor(mx, 1, 16)); mx = fmaxf(mx, __shfl_xor(mx, 2, 16));
  mx = fmaxf(mx, __shfl_xor(mx, 4, 16)); mx = fmaxf(mx, __shfl_xor(mx, 8, 16));
  const float e = expf(logit - mx);
  float den = e;
  den += __shfl_xor(den, 1, 16); den += __shfl_xor(den, 2, 16);
  den += __shfl_xor(den, 4, 16); den += __shfl_xor(den, 8, 16);
  const float att = e / den;

#pragma unroll
  for (int c = 0; c < 64; ++c){       // pooled (replicated on all 16 lanes)
    float p = feat[c] * att;
    p += __shfl_xor(p, 1, 16); p += __shfl_xor(p, 2, 16);
    p += __shfl_xor(p, 4, 16); p += __shfl_xor(p, 8, 16);
    feat[c] = p;
  }

  const float X0[4] = {cx, cy, cz, cw};
#pragma unroll
  for (int jj = 0; jj < 4; ++jj){
    const int j = k * 4 + jj;
    float f1 = 0.f;
#pragma unroll
    for (int c = 0; c < 64; ++c) f1 = fmaf(b1_w[j * 64 + c], feat[c], f1);
    float f2 = 0.f;
#pragma unroll
    for (int c = 0; c < 4; ++c) f2 = fmaf(b2_w[j * 4 + c], X0[c], f2);
    ob[4 + j][spl] = leaky(f1 + f2, 0.1f);
  }
  if (k == 0){
    ob[0][spl] = cx; ob[1][spl] = cy; ob[2][spl] = cz; ob[3][spl] = cw;
  }
  __syncthreads();
  float* outb = out + (size_t)b * 68 * Sn;
  for (int e2 = tid; e2 < 68 * 16; e2 += 256){
    const int r = e2 >> 4, c = e2 & 15;
    outb[(size_t)r * Sn + sp0 + c] = ob[r][c];
  }
}

extern "C" void kernel_launch(void* const* d_in, const int* in_sizes, int n_in,
                              void* d_out, int out_size, void* d_ws, size_t ws_size,
                              hipStream_t stream){
  const float* x      = (const float*)d_in[0];
  const int*   perm   = (const int*)d_in[1];
  const float* pos_w  = (const float*)d_in[3];
  const float* bn2_g  = (const float*)d_in[4];
  const float* bn2_b  = (const float*)d_in[5];
  const float* conv_w = (const float*)d_in[6];
  const float* bn_g   = (const float*)d_in[7];
  const float* bn_b   = (const float*)d_in[8];
  const float* att_w1 = (const float*)d_in[9];
  const float* att_w2 = (const float*)d_in[10];
  const float* b1_w   = (const float*)d_in[11];
  const float* b2_w   = (const float*)d_in[12];
  float* out = (float*)d_out;

  char* ws = (char*)d_ws;
  int*    idx       = (int*)ws;                    // 2 MiB
  float4* pk        = (float4*)(ws + 2097152);     // 1 MiB
  float4* spt       = (float4*)(ws + 3145728);     // 1 MiB
  int*    sid       = (int*)(ws + 4194304);        // 256 KiB
  int*    hist      = (int*)(ws + 4456448);        // 128 KiB (8*NCELL)
  int*    cellstart = (int*)(ws + 4587520);        // 128+ KiB (8*(NCELL+1))
  int*    cursor    = (int*)(ws + 4718848);        // 128+ KiB
  int*    qord      = (int*)(ws + 4850176);        // 128 KiB (B*Sn)
  float*  part      = (float*)(ws + 4981248);      // 384 KiB
  float2* stats     = (float2*)(ws + 5374464);     // 2 KiB

  hipMemsetAsync(hist, 0, Bn * 2 * NCELL * sizeof(int), stream);
  hipLaunchKernelGGL(k_pack,    dim3(256),          dim3(256),  0, stream, x, perm, pk, hist);
  hipLaunchKernelGGL(k_scan,    dim3(8),            dim3(1024), 0, stream, hist,
                     cellstart, cursor);
  hipLaunchKernelGGL(k_scatter, dim3(256),          dim3(256),  0, stream, pk, perm,
                     cursor, spt, sid, qord);
  hipLaunchKernelGGL(k_topk,    dim3(512, 4),       dim3(256),  0, stream, pk, spt, sid,
                     cellstart, perm, qord, idx);
  hipLaunchKernelGGL(k_stats,   dim3(ST_CHUNKS, 4), dim3(256),  0, stream, pk, x, idx, part);
  hipLaunchKernelGGL(k_stats2,  dim3(1),            dim3(640),  0, stream, part, pos_w, conv_w,
                     bn2_g, bn2_b, bn_g, bn_b, stats);
  hipLaunchKernelGGL(k_final,   dim3(512, 4),       dim3(256),  0, stream, pk, x, idx, stats,
                     conv_w, pos_w, att_w1, att_w2, b1_w, b2_w, out);
}

// Round 16
// 253.570 us; speedup vs baseline: 1.1182x; 1.1182x over previous
//
#include <hip/hip_runtime.h>
#include <math.h>

#define DEVI static __device__ __forceinline__

constexpr int Bn = 4, Cn = 4, Pn = 16384, Sn = 8192, Kn = 16;
constexpr float GN_N = 131072.0f;   // S*K per (b,channel)
constexpr int PART_STRIDE = 96;     // 79 used
constexpr int ST_CHUNKS = 256;      // k_stats grid.x
constexpr int GD = 16;              // grid cells per dim
constexpr int NCELL = GD * GD * GD; // 4096
constexpr float BND = 5.5f;         // fixed bounds (edge cells extend to inf)
constexpr float CH = 0.6875f;       // 11/16, exact in f32
constexpr float INVH = 1.4545455f;  // 16/11 (binning only; consistent everywhere)
constexpr float SLACK = 1e-3f;      // >> pd-vs-exact-dist rounding gap (~2e-5)

// non-contracted f32 ops (exact pd must match np's mul/add order)
DEVI float mulrn(float a, float b){ return __fmul_rn(a, b); }
DEVI float addrn(float a, float b){ return __fadd_rn(a, b); }
DEVI float subrn(float a, float b){ return __fsub_rn(a, b); }
DEVI float leaky(float v, float s){ return v >= 0.0f ? v : s * v; }

DEVI int clampi(int v, int lo, int hi){ return v < lo ? lo : (v > hi ? hi : v); }

// DPP move with zero-fill (bound_ctrl=1); ctrl must be a compile-time imm
template<int CTRL>
DEVI float dppmovf(float x){
  int xi = __builtin_bit_cast(int, x);
  int r = __builtin_amdgcn_update_dpp(0, xi, CTRL, 0xF, 0xF, true);
  return __builtin_bit_cast(float, r);
}
// DPP row_shr:1 == shfl_up(x,1,16) within each 16-lane row (group == row).
DEVI float dpp_up1f(float x){
  int xi = __builtin_bit_cast(int, x);
  int r = __builtin_amdgcn_update_dpp(xi, xi, 0x111, 0xF, 0xF, false);
  return __builtin_bit_cast(float, r);
}
DEVI int dpp_up1i(int x){
  return __builtin_amdgcn_update_dpp(x, x, 0x111, 0xF, 0xF, false);
}
// lane (i|15) broadcast within each 16-lane group
DEVI float swz15(float x){
  int xi = __builtin_bit_cast(int, x);
  int r = __builtin_amdgcn_ds_swizzle(xi, 0x1FF);
  return __builtin_bit_cast(float, r);
}
DEVI int swz15i(int x){ return __builtin_amdgcn_ds_swizzle(x, 0x1FF); }

// 16-lane sum via pure-DPP butterfly (quad xor1, xor2, half-mirror, mirror)
DEVI float red16(float v){
  v += dppmovf<0xB1>(v);   // quad_perm [1,0,3,2]  (xor 1)
  v += dppmovf<0x4E>(v);   // quad_perm [2,3,0,1]  (xor 2)
  v += dppmovf<0x141>(v);  // row_half_mirror
  v += dppmovf<0x140>(v);  // row_mirror
  return v;                // all 16 lanes hold the sum
}
DEVI float red16max(float v){
  v = fmaxf(v, dppmovf<0xB1>(v));
  v = fmaxf(v, dppmovf<0x4E>(v));
  v = fmaxf(v, dppmovf<0x141>(v));
  v = fmaxf(v, dppmovf<0x140>(v));
  return v;
}
// full-wave (64-lane) sum via DPP; result valid in lane 63
DEVI float wredD(float v){
  v += dppmovf<0x111>(v);  // row_shr:1
  v += dppmovf<0x112>(v);  // row_shr:2
  v += dppmovf<0x114>(v);  // row_shr:4
  v += dppmovf<0x118>(v);  // row_shr:8
  v += dppmovf<0x142>(v);  // row_bcast15
  v += dppmovf<0x143>(v);  // row_bcast31
  return v;
}

// cell binning — identical function used by hist/scatter/query
DEVI int cellof(float4 v, int &cx, int &cy, int &cz){
  cx = clampi((int)((v.x + BND) * INVH), 0, GD - 1);
  cy = clampi((int)((v.y + BND) * INVH), 0, GD - 1);
  cz = clampi((int)((v.z + BND) * INVH), 0, GD - 1);
  return (cx * GD + cy) * GD + cz;
}

// min dist^2 contribution of one dim; edge cells extend outward to infinity
DEVI float cm1(float q, int c){
  float lo = -BND + c * CH, hi = lo + CH;
  float d = 0.f;
  if (c > 0      && q < lo) d = lo - q;
  if (c < GD - 1 && q > hi) d = q - hi;
  return d * d;
}

// ---------------- K1: pack coords + norm into float4; zero hists -----------
// hist units u in [0,8): u = b (points), u = 4+b (queries)
__global__ void k_pack(const float* __restrict__ x, float4* __restrict__ pk,
                       int* __restrict__ hist){
  int i = blockIdx.x * 256 + threadIdx.x;       // 0 .. B*P-1
  int b = i >> 14, p = i & (Pn - 1);
  const float* xb = x + (size_t)b * Cn * Pn;
  float x0 = xb[p], x1 = xb[Pn + p], x2 = xb[2 * Pn + p];
  float n = addrn(addrn(mulrn(x0, x0), mulrn(x1, x1)), mulrn(x2, x2));
  pk[i] = make_float4(x0, x1, x2, n);
  if (i < Bn * 2 * NCELL) hist[i] = 0;          // 32768 ints
}

// ---------------- K1b: point + query histograms ----------------
__global__ void k_hist(const float4* __restrict__ pk, const int* __restrict__ perm,
                       int* __restrict__ hist){
  int i = blockIdx.x * 256 + threadIdx.x;
  int b = i >> 14;
  int cx, cy, cz;
  int c = cellof(pk[i], cx, cy, cz);
  atomicAdd(&hist[b * NCELL + c], 1);
  if (i < Bn * Sn){
    int b2 = i >> 13;
    int q = perm[i];
    int c2 = cellof(pk[b2 * Pn + q], cx, cy, cz);
    atomicAdd(&hist[(4 + b2) * NCELL + c2], 1);
  }
}

// ---------------- K1c: exclusive scan per unit (8 units x 4096 cells) ------
__launch_bounds__(1024)
__global__ void k_scan(const int* __restrict__ hist, int* __restrict__ cellstart,
                       int* __restrict__ cursor){
  __shared__ int sh[1024];
  const int u = blockIdx.x, t = threadIdx.x;
  const int base = u * NCELL + t * 4;
  int sum = 0;
#pragma unroll
  for (int i = 0; i < 4; ++i) sum += hist[base + i];
  sh[t] = sum;
  __syncthreads();
  for (int off = 1; off < 1024; off <<= 1){
    int v = (t >= off) ? sh[t - off] : 0;
    __syncthreads();
    sh[t] += v;
    __syncthreads();
  }
  int run = sh[t] - sum;                        // exclusive
  const int cbase = u * (NCELL + 1) + t * 4;
#pragma unroll
  for (int i = 0; i < 4; ++i){
    cellstart[cbase + i] = run;
    cursor[cbase + i] = run;
    run += hist[base + i];
  }
  if (t == 1023) cellstart[u * (NCELL + 1) + NCELL] = run;
}

// ---------------- K1d: scatter points into cell order; sort queries --------
__global__ void k_scatter(const float4* __restrict__ pk, const int* __restrict__ perm,
                          int* __restrict__ cursor, float4* __restrict__ spt,
                          int* __restrict__ sid, int* __restrict__ qord){
  int i = blockIdx.x * 256 + threadIdx.x;
  int b = i >> 14, p = i & (Pn - 1);
  float4 v = pk[i];
  int cx, cy, cz;
  int c = cellof(v, cx, cy, cz);
  int slot = atomicAdd(&cursor[b * (NCELL + 1) + c], 1);
  spt[b * Pn + slot] = v;
  sid[b * Pn + slot] = p;
  if (i < Bn * Sn){
    int b2 = i >> 13, s = i & (Sn - 1);
    int q = perm[i];
    int c2 = cellof(pk[b2 * Pn + q], cx, cy, cz);
    int slot2 = atomicAdd(&cursor[(4 + b2) * (NCELL + 1) + c2], 1);
    qord[b2 * Sn + slot2] = s;                  // queries sorted by cell
  }
}

// ---------------- K2: exact top-16 per (b,s): grid prune + 16-lane group ---
// (R13-verbatim: 131 us proven) 16 lanes per query; 16 cell-sorted queries
// per block; cellstart table in LDS; column-level prune + column-empty test.
#define VISITC(CX, CY, CZ, BXY)                                               \
  { const float m2_ = (BXY) + cm1(qz, (CZ));                                  \
    if (!(t15 > -1e37f) || -m2_ >= t15 - SLACK){                              \
      const int c_ = ((CX) * GD + (CY)) * GD + (CZ);                          \
      const int j0_ = lcs[c_], j1_ = lcs[c_ + 1];                             \
      for (int j = j0_ + lane16; j - lane16 < j1_; j += 16){                  \
        float cpd = -INFINITY; int cpi = 0x7FFFFFFF;                          \
        if (j < j1_){                                                         \
          const float4 v = spt[pb + j];                                       \
          const float dot = addrn(addrn(mulrn(v.x, qx), mulrn(v.y, qy)),      \
                                  mulrn(v.z, qz));                            \
          cpd = subrn(subrn(mulrn(2.0f, dot), v.w), qw);                      \
          cpi = sid[pb + j];                                                  \
        }                                                                     \
        const unsigned long long m0 =                                         \
          __ballot((cpd > t15) || (cpd == t15 && cpi < i15)) & gmask;         \
        unsigned long long mm = m0;                                           \
        while (mm){                                                           \
          const int src = __builtin_ctzll(mm);                                \
          mm &= mm - 1;                                                       \
          const float cv = __shfl(cpd, src);                                  \
          const int   ci = __shfl(cpi, src);                                  \
          const float upv = dpp_up1f(lv);                                     \
          const int   upi = dpp_up1i(li);                                     \
          const bool keep = (lv > cv) || (lv == cv && li < ci);               \
          const bool ins  = (!keep) &&                                        \
            (lane0 || (upv > cv) || (upv == cv && upi < ci));                 \
          lv = keep ? lv : (ins ? cv : upv);                                  \
          li = keep ? li : (ins ? ci : upi);                                  \
        }                                                                     \
        if (m0){ t15 = swz15(lv); i15 = swz15i(li); }                         \
      }                                                                       \
    } }

__launch_bounds__(256)
__global__ void k_topk(const float4* __restrict__ pk, const float4* __restrict__ spt,
                       const int* __restrict__ sid, const int* __restrict__ cellstart,
                       const int* __restrict__ perm, const int* __restrict__ qord,
                       int* __restrict__ idx){
  __shared__ int lcs[NCELL + 1];                // 16388 B: whole batch table
  const int b = blockIdx.y;
  const int tid = threadIdx.x;
  const int lane = tid & 63;
  const int lane16 = lane & 15;
  const bool lane0 = (lane16 == 0);
  const int g = lane >> 4;
  const unsigned long long gmask = 0xFFFFull << (g * 16);
  const int s = qord[b * Sn + blockIdx.x * 16 + (tid >> 4)];  // sorted query

  const int cb = b * (NCELL + 1);
  for (int j = tid; j <= NCELL; j += 256) lcs[j] = cellstart[cb + j];

  const int q = perm[b * Sn + s];
  const float4 sv = pk[b * Pn + q];
  const float qx = sv.x, qy = sv.y, qz = sv.z, qw = sv.w;
  int qcx, qcy, qcz;
  cellof(sv, qcx, qcy, qcz);
  const int pb = b * Pn;
  __syncthreads();

  float lv = -INFINITY;  int li = 0x7FFFFFFF;   // my rank's (value, index)
  float t15 = -INFINITY; int i15 = 0x7FFFFFFF;  // rank-15 key (group-uniform)

  for (int r = 0; r < GD; ++r){
    if (r >= 1 && t15 > -1e37f){
      const float lb = (float)(r - 1) * CH;
      if (-(lb * lb) < t15 - SLACK) break;      // no farther shell can matter
    }
    const int x0 = clampi(qcx - r, 0, GD - 1), x1 = clampi(qcx + r, 0, GD - 1);
    const int y0 = clampi(qcy - r, 0, GD - 1), y1 = clampi(qcy + r, 0, GD - 1);
    for (int cx = x0; cx <= x1; ++cx){
      const int adx = cx > qcx ? cx - qcx : qcx - cx;
      const float bx = cm1(qx, cx);
      for (int cy = y0; cy <= y1; ++cy){
        const int ady = cy > qcy ? cy - qcy : qcy - cy;
        const float bxy = bx + cm1(qy, cy);
        // column prune: z-contribution >= 0, so bxy bounds the whole column
        if ((t15 > -1e37f) && -bxy < t15 - SLACK) continue;
        if (adx == r || ady == r){              // full z-column is on the shell
          const int z0c = clampi(qcz - r, 0, GD - 1);
          const int z1c = clampi(qcz + r, 0, GD - 1);
          const int colb = (cx * GD + cy) * GD;
          if (lcs[colb + z0c] == lcs[colb + z1c + 1]) continue;  // column empty
          for (int cz = z0c; cz <= z1c; ++cz) VISITC(cx, cy, cz, bxy)
        } else {                                // only |dz| == r on the shell
          int cz = qcz - r;
          if (cz >= 0) VISITC(cx, cy, cz, bxy)
          cz = qcz + r;
          if (cz <= GD - 1) VISITC(cx, cy, cz, bxy)
        }
      }
    }
  }

  idx[((size_t)(b * Sn + s)) * Kn + lane16] = li;
}
#undef VISITC

// scramble: x1[b,c,s',k'] = x[b,c, idx[b, (16s'+k') & 8191, (16s'+k') >> 13]]
DEVI int idxq(const int* __restrict__ idxb, int f){
  return idxb[(f & (Sn - 1)) * Kn + (f >> 13)];
}

// ---------------- K3: GN moment accumulation ----------------
// grid (256, B), block 256: thread -> (sp, kq); sp = chunk*32 + tid>>3, 2 k's.
// Wave reductions via DPP (no DS traffic); result lane = 63.
__global__ void k_stats(const float4* __restrict__ pk, const float* __restrict__ x,
                        const int* __restrict__ idx, float* __restrict__ part){
  const int b = blockIdx.y, chunk = blockIdx.x, tid = threadIdx.x;
  const int sp = chunk * 32 + (tid >> 3);
  const int kq = tid & 7;
  const int* idxb = idx + b * Sn * Kn;
  const float* xw = x + ((size_t)b * Cn + 3) * Pn;

  float M10[55], mu10[10], M4[10], mu4[4];
#pragma unroll
  for (int i = 0; i < 55; ++i) M10[i] = 0.f;
#pragma unroll
  for (int i = 0; i < 10; ++i){ mu10[i] = 0.f; M4[i] = 0.f; }
#pragma unroll
  for (int i = 0; i < 4; ++i) mu4[i] = 0.f;

  const int qc = idxq(idxb, sp * 16);
  const float4 cv = pk[b * Pn + qc];

#pragma unroll
  for (int kk = 0; kk < 2; ++kk){
    const int k = kq * 2 + kk;
    const int qn = idxq(idxb, sp * 16 + k);
    const float4 pv = pk[b * Pn + qn];
    const float pw = xw[qn];
    const float dx = subrn(pv.x, cv.x), dy = subrn(pv.y, cv.y), dz = subrn(pv.z, cv.z);
    const float temp = sqrtf(addrn(addrn(mulrn(dx, dx), mulrn(dy, dy)), mulrn(dz, dz)));
    const float E[10] = {pv.x, pv.y, pv.z, cv.x, cv.y, cv.z, dx, dy, dz, temp};
    const float X[4]  = {pv.x, pv.y, pv.z, pw};
    int c = 0;
#pragma unroll
    for (int i = 0; i < 10; ++i){
      mu10[i] += E[i];
#pragma unroll
      for (int j = i; j < 10; ++j){ M10[c] += E[i] * E[j]; ++c; }
    }
    c = 0;
#pragma unroll
    for (int i = 0; i < 4; ++i){
      mu4[i] += X[i];
#pragma unroll
      for (int j = i; j < 4; ++j){ M4[c] += X[i] * X[j]; ++c; }
    }
  }

  __shared__ float red[4][80];
  const int wid = tid >> 6, ln = tid & 63;
#pragma unroll
  for (int i = 0; i < 55; ++i){ float v = wredD(M10[i]); if (ln == 63) red[wid][i] = v; }
#pragma unroll
  for (int i = 0; i < 10; ++i){ float v = wredD(mu10[i]); if (ln == 63) red[wid][55 + i] = v; }
#pragma unroll
  for (int i = 0; i < 10; ++i){ float v = wredD(M4[i]); if (ln == 63) red[wid][65 + i] = v; }
#pragma unroll
  for (int i = 0; i < 4; ++i){ float v = wredD(mu4[i]); if (ln == 63) red[wid][75 + i] = v; }
  __syncthreads();
  if (tid < 79){
    float sum = ((red[0][tid] + red[1][tid]) + red[2][tid]) + red[3][tid];
    part[(b * ST_CHUNKS + chunk) * PART_STRIDE + tid] = sum;
  }
}

// ---------------- K4: fold moments into per-(b,ch) scale/shift ----------------
__global__ void k_stats2(const float* __restrict__ part,
                         const float* __restrict__ pos_w, const float* __restrict__ conv_w,
                         const float* __restrict__ bn2_g, const float* __restrict__ bn2_b,
                         const float* __restrict__ bn_g,  const float* __restrict__ bn_b,
                         float2* __restrict__ stats){
  __shared__ float phalf[8][80];
  __shared__ float sacc[4][80];
  const int t = threadIdx.x;
  if (t < 640){
    const int pair = t / 80, i = t % 80;      // pair = b*2 + half
    if (i < 79){
      const int bb = pair >> 1, half = pair & 1;
      float a = 0.f;
      for (int c = half * 128; c < half * 128 + 128; ++c)
        a += part[(bb * ST_CHUNKS + c) * PART_STRIDE + i];
      phalf[pair][i] = a;
    }
  }
  __syncthreads();
  if (t < 320){
    const int bb = t / 80, i = t % 80;
    if (i < 79) sacc[bb][i] = phalf[bb * 2][i] + phalf[bb * 2 + 1][i];
  }
  __syncthreads();
  if (t >= 256) return;
  const int b = t >> 6, o = t & 63;
  const float* acc = sacc[b];
  float mean, ex2, gamma, beta;
  if (o < 32){                        // xc channels: conv path, bn_g/bn_b
    const float* w = conv_w + o * 4;
    float m = 0.f, e2 = 0.f; int id = 0;
#pragma unroll
    for (int i = 0; i < 4; ++i){
      m += w[i] * acc[75 + i];
#pragma unroll
      for (int j = i; j < 4; ++j){
        float t2 = w[i] * w[j] * acc[65 + id];
        e2 += (i == j) ? t2 : 2.0f * t2; ++id;
      }
    }
    mean = m / GN_N; ex2 = e2 / GN_N; gamma = bn_g[o]; beta = bn_b[o];
  } else {                            // pe channels: pos path, bn2_g/bn2_b
    const float* w = pos_w + (o - 32) * 10;
    float m = 0.f, e2 = 0.f; int id = 0;
#pragma unroll
    for (int i = 0; i < 10; ++i){
      m += w[i] * acc[55 + i];
#pragma unroll
      for (int j = i; j < 10; ++j){
        float t2 = w[i] * w[j] * acc[id];
        e2 += (i == j) ? t2 : 2.0f * t2; ++id;
      }
    }
    mean = m / GN_N; ex2 = e2 / GN_N; gamma = bn2_g[o - 32]; beta = bn2_b[o - 32];
  }
  const float var = fmaxf(ex2 - mean * mean, 0.f);
  const float rstd = 1.0f / sqrtf(var + 1e-5f);
  const float scale = rstd * gamma;
  stats[b * 64 + o] = make_float2(scale, beta - mean * scale);
}

// ---------------- K5: fused features + attention + output ----------------
// 16 lanes per s'; block = 16 s'. All 16-lane reductions via DPP (no DS
// traffic); output staged in padded LDS, written as 64B row-segments.
__global__ void k_final(const float4* __restrict__ pk, const float* __restrict__ x,
                        const int* __restrict__ idx, const float2* __restrict__ stats,
                        const float* __restrict__ conv_w, const float* __restrict__ pos_w,
                        const float* __restrict__ att_w1, const float* __restrict__ att_w2,
                        const float* __restrict__ b1_w, const float* __restrict__ b2_w,
                        float* __restrict__ out){
  __shared__ float ob[68][17];                  // +1 pad: conflict-free stores
  const int b = blockIdx.y;
  const int tid = threadIdx.x;
  const int k = tid & 15;
  const int spl = tid >> 4;
  const int sp0 = blockIdx.x * 16;
  const int sp = sp0 + spl;
  const int* idxb = idx + b * Sn * Kn;
  const float* xw = x + ((size_t)b * Cn + 3) * Pn;

  const int qn = idxq(idxb, sp * 16 + k);
  const float4 pv = pk[b * Pn + qn];
  const float pw = xw[qn];
  const float cx = __shfl(pv.x, 0, 16), cy = __shfl(pv.y, 0, 16);
  const float cz = __shfl(pv.z, 0, 16), cw = __shfl(pw, 0, 16);
  const float dx = subrn(pv.x, cx), dy = subrn(pv.y, cy), dz = subrn(pv.z, cz);
  const float temp = sqrtf(addrn(addrn(mulrn(dx, dx), mulrn(dy, dy)), mulrn(dz, dz)));
  const float E[10]  = {pv.x, pv.y, pv.z, cx, cy, cz, dx, dy, dz, temp};
  const float X4[4]  = {pv.x, pv.y, pv.z, pw};
  const float2* stb = stats + b * 64;

  float feat[64];
  for (int o = 0; o < 32; ++o){       // xc
    float v = 0.f;
#pragma unroll
    for (int c = 0; c < 4; ++c) v = fmaf(conv_w[o * 4 + c], X4[c], v);
    const float2 sc = stb[o];
    feat[o] = leaky(fmaf(v, sc.x, sc.y), 0.2f);
  }
  for (int o = 0; o < 32; ++o){       // pe
    float v = 0.f;
#pragma unroll
    for (int c = 0; c < 10; ++c) v = fmaf(pos_w[o * 10 + c], E[c], v);
    const float2 sc = stb[32 + o];
    feat[32 + o] = leaky(fmaf(v, sc.x, sc.y), 0.2f);
  }

  float logit = 0.f;
  for (int h = 0; h < 32; ++h){
    float v = 0.f;
#pragma unroll
    for (int c = 0; c < 64; ++c) v = fmaf(att_w1[h * 64 + c], feat[c], v);
    logit = fmaf(att_w2[h], leaky(v, 0.2f), logit);
  }
  const float mx = red16max(logit);
  const float e = expf(logit - mx);
  const float den = red16(e);
  const float att = e / den;

#pragma unroll
  for (int c = 0; c < 64; ++c)        // pooled (replicated on all 16 lanes)
    feat[c] = red16(feat[c] * att);

  const float X0[4] = {cx, cy, cz, cw};
#pragma unroll
  for (int jj = 0; jj < 4; ++jj){
    const int j = k * 4 + jj;
    float f1 = 0.f;
#pragma unroll
    for (int c = 0; c < 64; ++c) f1 = fmaf(b1_w[j * 64 + c], feat[c], f1);
    float f2 = 0.f;
#pragma unroll
    for (int c = 0; c < 4; ++c) f2 = fmaf(b2_w[j * 4 + c], X0[c], f2);
    ob[4 + j][spl] = leaky(f1 + f2, 0.1f);
  }
  if (k == 0){
    ob[0][spl] = cx; ob[1][spl] = cy; ob[2][spl] = cz; ob[3][spl] = cw;
  }
  __syncthreads();
  float* outb = out + (size_t)b * 68 * Sn;
  for (int e2 = tid; e2 < 68 * 16; e2 += 256){
    const int r = e2 >> 4, c = e2 & 15;
    outb[(size_t)r * Sn + sp0 + c] = ob[r][c];
  }
}

extern "C" void kernel_launch(void* const* d_in, const int* in_sizes, int n_in,
                              void* d_out, int out_size, void* d_ws, size_t ws_size,
                              hipStream_t stream){
  const float* x      = (const float*)d_in[0];
  const int*   perm   = (const int*)d_in[1];
  const float* pos_w  = (const float*)d_in[3];
  const float* bn2_g  = (const float*)d_in[4];
  const float* bn2_b  = (const float*)d_in[5];
  const float* conv_w = (const float*)d_in[6];
  const float* bn_g   = (const float*)d_in[7];
  const float* bn_b   = (const float*)d_in[8];
  const float* att_w1 = (const float*)d_in[9];
  const float* att_w2 = (const float*)d_in[10];
  const float* b1_w   = (const float*)d_in[11];
  const float* b2_w   = (const float*)d_in[12];
  float* out = (float*)d_out;

  char* ws = (char*)d_ws;
  int*    idx       = (int*)ws;                    // 2 MiB
  float4* pk        = (float4*)(ws + 2097152);     // 1 MiB
  float4* spt       = (float4*)(ws + 3145728);     // 1 MiB
  int*    sid       = (int*)(ws + 4194304);        // 256 KiB
  int*    hist      = (int*)(ws + 4456448);        // 128 KiB (8*NCELL)
  int*    cellstart = (int*)(ws + 4587520);        // 128+ KiB (8*(NCELL+1))
  int*    cursor    = (int*)(ws + 4718848);        // 128+ KiB
  int*    qord      = (int*)(ws + 4850176);        // 128 KiB (B*Sn)
  float*  part      = (float*)(ws + 4981248);      // 384 KiB
  float2* stats     = (float2*)(ws + 5374464);     // 2 KiB

  hipLaunchKernelGGL(k_pack,    dim3(256),          dim3(256),  0, stream, x, pk, hist);
  hipLaunchKernelGGL(k_hist,    dim3(256),          dim3(256),  0, stream, pk, perm, hist);
  hipLaunchKernelGGL(k_scan,    dim3(8),            dim3(1024), 0, stream, hist,
                     cellstart, cursor);
  hipLaunchKernelGGL(k_scatter, dim3(256),          dim3(256),  0, stream, pk, perm,
                     cursor, spt, sid, qord);
  hipLaunchKernelGGL(k_topk,    dim3(512, 4),       dim3(256),  0, stream, pk, spt, sid,
                     cellstart, perm, qord, idx);
  hipLaunchKernelGGL(k_stats,   dim3(ST_CHUNKS, 4), dim3(256),  0, stream, pk, x, idx, part);
  hipLaunchKernelGGL(k_stats2,  dim3(1),            dim3(640),  0, stream, part, pos_w, conv_w,
                     bn2_g, bn2_b, bn_g, bn_b, stats);
  hipLaunchKernelGGL(k_final,   dim3(512, 4),       dim3(256),  0, stream, pk, x, idx, stats,
                     conv_w, pos_w, att_w1, att_w2, b1_w, b2_w, out);
}